// Round 15
// baseline (208.507 us; speedup 1.0000x reference)
//
#include <hip/hip_runtime.h>
#include <hip/hip_bf16.h>
#include <math.h>

#define BB 8
#define NN 1024
#define FF 256
#define HH 8
#define OO 64
#define CC 256

typedef __attribute__((ext_vector_type(8))) short short8;
typedef __attribute__((ext_vector_type(4))) short s16x4;
typedef __attribute__((ext_vector_type(4))) float f32x4;
typedef unsigned long long u64;

__device__ __forceinline__ short bf16s(float f) {
    __hip_bfloat16 h = __float2bfloat16(f);
    return *reinterpret_cast<short*>(&h);
}

// ---------- combined one-time prep: adj bitmask | x->bf16 | weight transposes ----
__global__ void k_prep(const int* __restrict__ adj, const float* __restrict__ x,
                       const float* __restrict__ Wa, const float* __restrict__ Wo,
                       u64* __restrict__ adjbit, __hip_bfloat16* __restrict__ xbf,
                       __hip_bfloat16* __restrict__ WaT, __hip_bfloat16* __restrict__ WoT) {
    int bid = blockIdx.x, t = threadIdx.x;
    if (bid < 32768) {                       // adj -> bitmask
        int i = bid * 256 + t;
        u64 m = __ballot(adj[i] > 0);
        if ((t & 63) == 0) adjbit[i >> 6] = m;
    } else if (bid < 32768 + 8192) {         // x -> bf16
        int i = (bid - 32768) * 256 + t;
        xbf[i] = __float2bfloat16(x[i]);
    } else {                                 // weight transposes
        int i = (bid - 32768 - 8192) * 256 + t;
        if (i < 131072) {
            int hd = i >> 14, o = (i >> 8) & 63, f = i & 255;
            WaT[i] = __float2bfloat16(Wa[hd * 16384 + f * 64 + o]);
        } else {
            int j = i - 131072;
            int c = j >> 9, k = j & 511;
            WoT[j] = __float2bfloat16(Wo[k * 256 + c]);
        }
    }
}

// ---------- MFMA proj: h = xbf @ W_att, fused f1/f2; h stored FRAGMENT-MAJOR ----
// hF block (bh, kw, cf, half) of 512 bf16: elem (g*16+r)*8+q holds
// h[n = kw*64 + half*32 + g*8 + q][o = cf*16 + r].
__global__ void k_proj_mfma(const __hip_bfloat16* __restrict__ xbf,
                            const __hip_bfloat16* __restrict__ WaT,
                            const float* __restrict__ aatt,
                            __hip_bfloat16* __restrict__ hF,
                            float* __restrict__ f1, float* __restrict__ f2) {
    int tile = blockIdx.x, hd = blockIdx.y;
    int t = threadIdx.x, lane = t & 63, w = t >> 6;
    int r0 = tile * 64;
    int b = r0 >> 10;
    int n0 = r0 & 1023;
    int bh = b * HH + hd;
    int al = lane & 15, ah = lane >> 4;
    const __hip_bfloat16* xrow = xbf + (size_t)(r0 + w * 16 + al) * FF;
    const __hip_bfloat16* Wb = WaT + (size_t)hd * OO * FF;
    f32x4 z4 = {0.f, 0.f, 0.f, 0.f};
    f32x4 acc[4] = {z4, z4, z4, z4};
    for (int k0 = 0; k0 < FF; k0 += 32) {
        int k = k0 + ah * 8;
        short8 af = *(const short8*)&xrow[k];
#pragma unroll
        for (int cf = 0; cf < 4; ++cf) {
            int col = cf * 16 + al;
            short8 bf = *(const short8*)&Wb[(size_t)col * FF + k];
            acc[cf] = __builtin_amdgcn_mfma_f32_16x16x32_bf16(af, bf, acc[cf], 0, 0, 0);
        }
    }
    int kw = tile & 15;
    int half = w >> 1;
    int hg = (w & 1) * 2 + (ah >> 1);
    int q0 = (ah & 1) * 4;
#pragma unroll
    for (int cf = 0; cf < 4; ++cf) {
        size_t base = ((((size_t)bh * 16 + kw) * 4 + cf) * 2 + half) * 512 +
                      (hg * 16 + al) * 8 + q0;
        s16x4 v;
#pragma unroll
        for (int r = 0; r < 4; ++r) v[r] = bf16s(acc[cf][r]);
        *(s16x4*)&hF[base] = v;
    }
    int nb = n0 + w * 16 + ah * 4;
    float p1[4] = {0.f, 0.f, 0.f, 0.f}, p2[4] = {0.f, 0.f, 0.f, 0.f};
#pragma unroll
    for (int cf = 0; cf < 4; ++cf) {
        int col = cf * 16 + al;
        float a1 = aatt[hd * 2 * OO + col];
        float a2 = aatt[hd * 2 * OO + OO + col];
#pragma unroll
        for (int r = 0; r < 4; ++r) {
            p1[r] += acc[cf][r] * a1;
            p2[r] += acc[cf][r] * a2;
        }
    }
#pragma unroll
    for (int off = 1; off < 16; off <<= 1) {
#pragma unroll
        for (int r = 0; r < 4; ++r) {
            p1[r] += __shfl_xor(p1[r], off);
            p2[r] += __shfl_xor(p2[r], off);
        }
    }
    if (al == 0) {
#pragma unroll
        for (int r = 0; r < 4; ++r) {
            f1[(size_t)bh * NN + nb + r] = p1[r];
            f2[(size_t)bh * NN + nb + r] = p2[r];
        }
    }
}

// ---------- FUSED att v6: 256 thr non-redundant A + double-buffered B prefetch --
__global__ void k_att_fused(const u64* __restrict__ adjbit, const float* __restrict__ f1,
                            const float* __restrict__ f2,
                            const __hip_bfloat16* __restrict__ hF,
                            __hip_bfloat16* __restrict__ ybf) {
    int orig = blockIdx.x;                     // 1024 blocks
    int wgid = (orig & 7) * 128 + (orig >> 3); // XCD-contiguous
    int bh = wgid >> 4;
    int n0 = (wgid & 15) * 64;
    int b = bh >> 3, hd = bh & 7;
    int t = threadIdx.x, lane = t & 63, w = t >> 6;
    __shared__ float Qs[1024], Ss[1024];
    __shared__ u64 bits[64 * 17];
    const float* f2b = f2 + (size_t)bh * NN;
    for (int j = t; j < 1024; j += 256) {
        float v = f2b[j];
        Qs[j] = __expf(v);
        Ss[j] = __expf(0.2f * v);
    }
    for (int e = t; e < 1024; e += 256) {
        int rr = e >> 4, c = e & 15;
        bits[rr * 17 + c] = adjbit[((size_t)b * NN + n0 + rr) * 16 + c];
    }
    int g = lane >> 4, r = lane & 15;
    int row = w * 16 + r;
    float fl = f1[(size_t)bh * NN + n0 + row];
    float P = __expf(fl), R = __expf(0.2f * fl);
    __syncthreads();
    const __hip_bfloat16* hFb = hF + (size_t)bh * 16 * 4 * 2 * 512 + lane * 8;
    f32x4 z4 = {0.f, 0.f, 0.f, 0.f};
    f32x4 acc[4] = {z4, z4, z4, z4};
    float ps = 0.f;
    int c0 = g * 8;
    auto BUILD = [&](int kw, short8& a0, short8& a1) {
        int k0 = kw * 64;
        u64 m = bits[row * 17 + kw];
        unsigned bl0 = (unsigned)(m >> c0) & 0xffu;
        unsigned bl1 = (unsigned)((m >> 32) >> c0) & 0xffu;
        f32x4 qa0 = *(const f32x4*)&Qs[k0 + c0];
        f32x4 qb0 = *(const f32x4*)&Qs[k0 + c0 + 4];
        f32x4 sa0 = *(const f32x4*)&Ss[k0 + c0];
        f32x4 sb0 = *(const f32x4*)&Ss[k0 + c0 + 4];
        f32x4 qa1 = *(const f32x4*)&Qs[k0 + 32 + c0];
        f32x4 qb1 = *(const f32x4*)&Qs[k0 + 32 + c0 + 4];
        f32x4 sa1 = *(const f32x4*)&Ss[k0 + 32 + c0];
        f32x4 sb1 = *(const f32x4*)&Ss[k0 + 32 + c0 + 4];
#pragma unroll
        for (int e = 0; e < 4; ++e) {
            float v0 = ((bl0 >> e) & 1) ? fmaxf(P * qa0[e], R * sa0[e]) : 0.f;
            float v1 = ((bl0 >> (4 + e)) & 1) ? fmaxf(P * qb0[e], R * sb0[e]) : 0.f;
            float v2 = ((bl1 >> e) & 1) ? fmaxf(P * qa1[e], R * sa1[e]) : 0.f;
            float v3 = ((bl1 >> (4 + e)) & 1) ? fmaxf(P * qb1[e], R * sb1[e]) : 0.f;
            ps += (v0 + v1) + (v2 + v3);
            a0[e] = bf16s(v0);
            a0[4 + e] = bf16s(v1);
            a1[e] = bf16s(v2);
            a1[4 + e] = bf16s(v3);
        }
    };
    auto LOADB = [&](int kw, short8* d0, short8* d1) {
#pragma unroll
        for (int cf = 0; cf < 4; ++cf) {
            const __hip_bfloat16* blk = hFb + ((size_t)(kw * 4 + cf) * 2) * 512;
            d0[cf] = *(const short8*)&blk[0];
            d1[cf] = *(const short8*)&blk[512];
        }
    };
    short8 pA0[4], pA1[4], pB0[4], pB1[4];
    LOADB(0, pA0, pA1);
    for (int kp = 0; kp < 8; ++kp) {
        short8 a0, a1;
        BUILD(2 * kp, a0, a1);
        LOADB(2 * kp + 1, pB0, pB1);
#pragma unroll
        for (int cf = 0; cf < 4; ++cf) {
            acc[cf] = __builtin_amdgcn_mfma_f32_16x16x32_bf16(a0, pA0[cf], acc[cf], 0, 0, 0);
            acc[cf] = __builtin_amdgcn_mfma_f32_16x16x32_bf16(a1, pA1[cf], acc[cf], 0, 0, 0);
        }
        BUILD(2 * kp + 1, a0, a1);
        if (kp < 7) LOADB(2 * kp + 2, pA0, pA1);
#pragma unroll
        for (int cf = 0; cf < 4; ++cf) {
            acc[cf] = __builtin_amdgcn_mfma_f32_16x16x32_bf16(a0, pB0[cf], acc[cf], 0, 0, 0);
            acc[cf] = __builtin_amdgcn_mfma_f32_16x16x32_bf16(a1, pB1[cf], acc[cf], 0, 0, 0);
        }
    }
    ps += __shfl_xor(ps, 16);
    ps += __shfl_xor(ps, 32);
#pragma unroll
    for (int rr = 0; rr < 4; ++rr) {
        int rloc = g * 4 + rr;
        float dn = __shfl(ps, rloc);
        float ids = 1.0f / dn;
        int nrow = n0 + w * 16 + rloc;
#pragma unroll
        for (int cf = 0; cf < 4; ++cf) {
            float v = acc[cf][rr] * ids;
            float e = v > 0.f ? v : expm1f(v);
            float yv = e > 0.f ? e : 0.01f * e;
            ybf[((size_t)b * NN + nrow) * 512 + hd * OO + cf * 16 + r] =
                __float2bfloat16(yv);
        }
    }
}

// ---------- MFMA outproj v2: 512 thr, 16-row tiles, 8 waves x 32 cols ----------
// hoF block (b, kw, cfB, half) of 512 bf16: elem (g*16+r)*8+q holds
// ho[n = kw*64 + half*32 + g*8 + q][c = cfB*16 + r].
__global__ void k_outproj_mfma(const __hip_bfloat16* __restrict__ ybf,
                               const __hip_bfloat16* __restrict__ WoT,
                               const float* __restrict__ ao,
                               __hip_bfloat16* __restrict__ hoF,
                               float* __restrict__ g1, float* __restrict__ g2) {
    int orig = blockIdx.x;                    // 512 blocks
    int tile = (orig & 7) * 64 + (orig >> 3); // XCD swizzle
    int t = threadIdx.x, lane = t & 63, w = t >> 6;   // 8 waves
    int r0 = tile * 16;
    int b = r0 >> 10;
    __shared__ __align__(16) __hip_bfloat16 As[16][520];
    __shared__ float pg1[8][16], pg2[8][16];
    for (int e = t; e < 1024; e += 512) {
        int row = e >> 6, k8 = (e & 63) * 8;
        *(short8*)&As[row][k8] = *(const short8*)&ybf[(size_t)(r0 + row) * 512 + k8];
    }
    __syncthreads();
    int al = lane & 15, ah = lane >> 4;
    f32x4 z4 = {0.f, 0.f, 0.f, 0.f};
    f32x4 acc[2] = {z4, z4};
    for (int k0 = 0; k0 < 512; k0 += 32) {
        int k = k0 + ah * 8;
        short8 a0 = *(const short8*)&As[al][k];
#pragma unroll
        for (int cf = 0; cf < 2; ++cf) {
            int col = w * 32 + cf * 16 + al;
            short8 bf = *(const short8*)&WoT[(size_t)col * 512 + k];
            acc[cf] = __builtin_amdgcn_mfma_f32_16x16x32_bf16(a0, bf, acc[cf], 0, 0, 0);
        }
    }
    int kw = (tile & 63) >> 2;
    int half = (tile >> 1) & 1;
    int hg0 = (tile & 1) * 2 + (ah >> 1);
    int q0 = (ah & 1) * 4;
    float q1[4] = {0.f, 0.f, 0.f, 0.f};
    float q2[4] = {0.f, 0.f, 0.f, 0.f};
#pragma unroll
    for (int cf = 0; cf < 2; ++cf) {
        int col = w * 32 + cf * 16 + al;
        int cfB = w * 2 + cf;
        float a1v = ao[col], a2v = ao[CC + col];
        size_t base = ((((size_t)b * 16 + kw) * 16 + cfB) * 2 + half) * 512;
        s16x4 v0;
#pragma unroll
        for (int r = 0; r < 4; ++r) {
            v0[r] = bf16s(acc[cf][r]);
            q1[r] += acc[cf][r] * a1v;
            q2[r] += acc[cf][r] * a2v;
        }
        *(s16x4*)&hoF[base + (hg0 * 16 + al) * 8 + q0] = v0;
    }
#pragma unroll
    for (int off = 1; off < 16; off <<= 1) {
#pragma unroll
        for (int j = 0; j < 4; ++j) {
            q1[j] += __shfl_xor(q1[j], off);
            q2[j] += __shfl_xor(q2[j], off);
        }
    }
    if (al == 0) {
#pragma unroll
        for (int j = 0; j < 4; ++j) {
            pg1[w][ah * 4 + j] = q1[j];
            pg2[w][ah * 4 + j] = q2[j];
        }
    }
    __syncthreads();
    if (t < 16) {
        float s1 = 0.f, s2 = 0.f;
#pragma unroll
        for (int ww = 0; ww < 8; ++ww) {
            s1 += pg1[ww][t];
            s2 += pg2[ww][t];
        }
        g1[r0 + t] = s1;
        g2[r0 + t] = s2;
    }
}

// ---------- FUSED out v9: wave = (k-quarter, col-half); A 2x (not 8x) redundant --
// 8 waves: kq = w>>1 owns k-windows 4kq..4kq+3; ch = w&1 owns cfB ch*8..+7.
// Partial acc[8] reduced via 2-round LDS tree; epilogue on waves 0/1.
__global__ void k_out_fused(const u64* __restrict__ adjbit, const float* __restrict__ g1,
                            const float* __restrict__ g2,
                            const __hip_bfloat16* __restrict__ hoF,
                            const float* __restrict__ xin, const int* __restrict__ mask,
                            const float* __restrict__ lw, const float* __restrict__ lb,
                            float* __restrict__ xout, __hip_bfloat16* __restrict__ xbfout,
                            float* __restrict__ outf, int final_) {
    int orig = blockIdx.x;                    // 512 blocks
    int wgid = (orig & 7) * 64 + (orig >> 3);
    int b = wgid >> 6;
    int n0 = (wgid & 63) * 16;
    int t = threadIdx.x, lane = t & 63, w = t >> 6;   // 8 waves
    int ch = w & 1, kq = w >> 1;
    __shared__ float Qs[1024], Ss[1024];
    __shared__ u64 bits[16 * 17];
    __shared__ f32x4 accbuf[4][8][64];        // 32 KB reduction buffer
    __shared__ float psbuf[4][64];
    __shared__ float lns[2][16], lnq[2][16];
    const float* g2b = g2 + (size_t)b * NN;
    for (int j = t; j < 1024; j += 512) {
        float v = g2b[j];
        Qs[j] = __expf(v);
        Ss[j] = __expf(0.2f * v);
    }
    if (t < 256) {
        int rr = t >> 4, c = t & 15;
        bits[rr * 17 + c] = adjbit[((size_t)b * NN + n0 + rr) * 16 + c];
    }
    int g = lane >> 4, r = lane & 15;
    float gl = g1[(size_t)b * NN + n0 + r];
    float P = __expf(gl);
    float R = __expf(0.2f * gl);
    __syncthreads();
    const __hip_bfloat16* hoFb = hoF + (size_t)b * 16 * 16 * 2 * 512 + lane * 8;
    f32x4 z4 = {0.f, 0.f, 0.f, 0.f};
    f32x4 acc[8] = {z4, z4, z4, z4, z4, z4, z4, z4};
    float ps = 0.f;
    int c0 = g * 8;
    auto BUILD = [&](int kw, short8& a0, short8& a1) {
        int k0 = kw * 64;
        u64 m = bits[r * 17 + kw];
        unsigned bl0 = (unsigned)(m >> c0) & 0xffu;
        unsigned bl1 = (unsigned)((m >> 32) >> c0) & 0xffu;
        f32x4 qa0 = *(const f32x4*)&Qs[k0 + c0];
        f32x4 qb0 = *(const f32x4*)&Qs[k0 + c0 + 4];
        f32x4 sa0 = *(const f32x4*)&Ss[k0 + c0];
        f32x4 sb0 = *(const f32x4*)&Ss[k0 + c0 + 4];
        f32x4 qa1 = *(const f32x4*)&Qs[k0 + 32 + c0];
        f32x4 qb1 = *(const f32x4*)&Qs[k0 + 32 + c0 + 4];
        f32x4 sa1 = *(const f32x4*)&Ss[k0 + 32 + c0];
        f32x4 sb1 = *(const f32x4*)&Ss[k0 + 32 + c0 + 4];
#pragma unroll
        for (int e = 0; e < 4; ++e) {
            float v0 = ((bl0 >> e) & 1) ? fmaxf(P * qa0[e], R * sa0[e]) : 0.f;
            float v1 = ((bl0 >> (4 + e)) & 1) ? fmaxf(P * qb0[e], R * sb0[e]) : 0.f;
            float v2 = ((bl1 >> e) & 1) ? fmaxf(P * qa1[e], R * sa1[e]) : 0.f;
            float v3 = ((bl1 >> (4 + e)) & 1) ? fmaxf(P * qb1[e], R * sb1[e]) : 0.f;
            ps += (v0 + v1) + (v2 + v3);
            a0[e] = bf16s(v0);
            a0[4 + e] = bf16s(v1);
            a1[e] = bf16s(v2);
            a1[4 + e] = bf16s(v3);
        }
    };
#pragma unroll
    for (int kwl = 0; kwl < 4; ++kwl) {
        int kw = kq * 4 + kwl;
        short8 a0, a1;
        BUILD(kw, a0, a1);
#pragma unroll
        for (int cf = 0; cf < 8; ++cf) {
            int cfB = ch * 8 + cf;
            const __hip_bfloat16* blk = hoFb + ((size_t)(kw * 16 + cfB) * 2) * 512;
            short8 b0 = *(const short8*)&blk[0];
            short8 b1 = *(const short8*)&blk[512];
            acc[cf] = __builtin_amdgcn_mfma_f32_16x16x32_bf16(a0, b0, acc[cf], 0, 0, 0);
            acc[cf] = __builtin_amdgcn_mfma_f32_16x16x32_bf16(a1, b1, acc[cf], 0, 0, 0);
        }
    }
    // per-wave partial rowsums: lane holds rowsum(row=lane&15) over its k-quarter
    ps += __shfl_xor(ps, 16);
    ps += __shfl_xor(ps, 32);
    // reduction round 1: waves 4..7 -> slots 0..3 (same-ch pairs: w and w+4)
    if (w >= 4) {
#pragma unroll
        for (int cf = 0; cf < 8; ++cf) accbuf[w - 4][cf][lane] = acc[cf];
        psbuf[w - 4][lane] = ps;
    }
    __syncthreads();
    if (w < 4) {
#pragma unroll
        for (int cf = 0; cf < 8; ++cf) acc[cf] += accbuf[w][cf][lane];
        ps += psbuf[w][lane];
    }
    __syncthreads();
    // round 2: waves 2,3 -> slots 0,1
    if (w == 2 || w == 3) {
#pragma unroll
        for (int cf = 0; cf < 8; ++cf) accbuf[w - 2][cf][lane] = acc[cf];
        psbuf[w - 2][lane] = ps;
    }
    __syncthreads();
    float tv[4][8];
    if (w < 2) {
#pragma unroll
        for (int cf = 0; cf < 8; ++cf) acc[cf] += accbuf[w][cf][lane];
        ps += psbuf[w][lane];
        // wave w (ch=w) now holds full sums for cols w*128..+127
#pragma unroll
        for (int rr = 0; rr < 4; ++rr) {
            int rloc = g * 4 + rr;
            float dn = __shfl(ps, rloc);
            float ids = 1.0f / dn;
            int nrow = n0 + rloc;
            int mk = mask[b * NN + nrow];
            size_t rowo = ((size_t)b * NN + nrow) * CC;
            float s1 = 0.f, s2 = 0.f;
#pragma unroll
            for (int cf = 0; cf < 8; ++cf) {
                int col = w * 128 + cf * 16 + r;
                float v = acc[cf][rr] * ids;
                float e = v > 0.f ? v : expm1f(v);
                float tvv = (mk == 0) ? 0.f : (xin[rowo + col] + e);
                tv[rr][cf] = tvv;
                s1 += tvv;
                s2 += tvv * tvv;
            }
#pragma unroll
            for (int off = 1; off < 16; off <<= 1) {
                s1 += __shfl_xor(s1, off);
                s2 += __shfl_xor(s2, off);
            }
            if (r == 0) {
                lns[w][rloc] = s1;
                lnq[w][rloc] = s2;
            }
        }
    }
    __syncthreads();
    if (w < 2) {
#pragma unroll
        for (int rr = 0; rr < 4; ++rr) {
            int rloc = g * 4 + rr;
            int nrow = n0 + rloc;
            size_t rowo = ((size_t)b * NN + nrow) * CC;
            float su = lns[0][rloc] + lns[1][rloc];
            float sq = lnq[0][rloc] + lnq[1][rloc];
            float mu = su * (1.0f / CC);
            float var = sq * (1.0f / CC) - mu * mu;
            float rstd = rsqrtf(var + 1e-5f);
#pragma unroll
            for (int cf = 0; cf < 8; ++cf) {
                int col = w * 128 + cf * 16 + r;
                float ln = (tv[rr][cf] - mu) * rstd * lw[col] + lb[col];
                if (final_) {
                    float rv = ln > 0.f ? ln : 0.f;
                    outf[rowo + col] = rv;
                    if (nrow == 0) outf[(size_t)BB * NN * CC + b * CC + col] = rv;
                } else {
                    xout[rowo + col] = ln;
                    xbfout[rowo + col] = __float2bfloat16(ln);
                }
            }
        }
    }
}

extern "C" void kernel_launch(void* const* d_in, const int* in_sizes, int n_in,
                              void* d_out, int out_size, void* d_ws, size_t ws_size,
                              hipStream_t stream) {
    const float* x = (const float*)d_in[0];
    const int* adj = (const int*)d_in[1];
    const int* mask = (const int*)d_in[2];
    const float* W_att = (const float*)d_in[3];
    const float* a_att = (const float*)d_in[4];
    const float* W_out = (const float*)d_in[5];
    const float* a_out = (const float*)d_in[6];
    const float* ln_w = (const float*)d_in[7];
    const float* ln_b = (const float*)d_in[8];
    float* out = (float*)d_out;

    float* ws = (float*)d_ws;
    float* xbuf = ws;                          // 2,097,152 f32
    float* xbfr = xbuf + 2097152;              // 2,097,152 f32 slot (xbf)
    float* f1   = xbfr + 2097152;              // 65,536
    float* f2   = f1 + 65536;                  // 65,536
    float* g1   = f2 + 65536;                  // 8,192
    float* g2   = g1 + 8192;                   // 8,192
    float* p    = g2 + 8192;
    __hip_bfloat16* xbf = (__hip_bfloat16*)xbfr;          // 2,097,152 bf16
    __hip_bfloat16* hF  = (__hip_bfloat16*)p;             // 4,194,304 bf16 (8 MB)
    __hip_bfloat16* ybf = (__hip_bfloat16*)(p + 2097152); // 4,194,304 bf16
    __hip_bfloat16* hoF = (__hip_bfloat16*)(p + 4194304); // 2,097,152 bf16 (4 MB)
    __hip_bfloat16* WaT = (__hip_bfloat16*)(p + 5242880); // 131,072 bf16
    __hip_bfloat16* WoT = (__hip_bfloat16*)(p + 5308416); // 131,072 bf16
    u64* adjbit = (u64*)(p + 5373952);                    // 131,072 u64 (1 MB)

    k_prep<<<32768 + 8192 + 1024, 256, 0, stream>>>(adj, x, W_att, W_out,
                                                    adjbit, xbf, WaT, WoT);

    for (int layer = 0; layer < 2; ++layer) {
        const float* xin_l = layer ? xbuf : x;
        k_proj_mfma<<<dim3(128, 8), 256, 0, stream>>>(xbf, WaT, a_att, hF, f1, f2);
        k_att_fused<<<1024, 256, 0, stream>>>(adjbit, f1, f2, hF, ybf);
        k_outproj_mfma<<<512, 512, 0, stream>>>(ybf, WoT, a_out, hoF, g1, g2);
        k_out_fused<<<512, 512, 0, stream>>>(adjbit, g1, g2, hoF, xin_l, mask,
                                             ln_w, ln_b, xbuf, xbf, out, layer == 1);
    }
}

// Round 16
// 193.415 us; speedup vs baseline: 1.0780x; 1.0780x over previous
//
#include <hip/hip_runtime.h>
#include <hip/hip_bf16.h>
#include <math.h>

#define BB 8
#define NN 1024
#define FF 256
#define HH 8
#define OO 64
#define CC 256

typedef __attribute__((ext_vector_type(8))) short short8;
typedef __attribute__((ext_vector_type(4))) short s16x4;
typedef __attribute__((ext_vector_type(4))) float f32x4;
typedef unsigned long long u64;

__device__ __forceinline__ short bf16s(float f) {
    __hip_bfloat16 h = __float2bfloat16(f);
    return *reinterpret_cast<short*>(&h);
}

// ---------- combined one-time prep: adj bitmask | x->bf16 | weight transposes ----
__global__ void k_prep(const int* __restrict__ adj, const float* __restrict__ x,
                       const float* __restrict__ Wa, const float* __restrict__ Wo,
                       u64* __restrict__ adjbit, __hip_bfloat16* __restrict__ xbf,
                       __hip_bfloat16* __restrict__ WaT, __hip_bfloat16* __restrict__ WoT) {
    int bid = blockIdx.x, t = threadIdx.x;
    if (bid < 32768) {                       // adj -> bitmask
        int i = bid * 256 + t;
        u64 m = __ballot(adj[i] > 0);
        if ((t & 63) == 0) adjbit[i >> 6] = m;
    } else if (bid < 32768 + 8192) {         // x -> bf16
        int i = (bid - 32768) * 256 + t;
        xbf[i] = __float2bfloat16(x[i]);
    } else {                                 // weight transposes
        int i = (bid - 32768 - 8192) * 256 + t;
        if (i < 131072) {
            int hd = i >> 14, o = (i >> 8) & 63, f = i & 255;
            WaT[i] = __float2bfloat16(Wa[hd * 16384 + f * 64 + o]);
        } else {
            int j = i - 131072;
            int c = j >> 9, k = j & 511;
            WoT[j] = __float2bfloat16(Wo[k * 256 + c]);
        }
    }
}

// ---------- MFMA proj: h = xbf @ W_att, fused f1/f2; h stored FRAGMENT-MAJOR ----
// hF block (bh, kw, cf, half) of 512 bf16: elem (g*16+r)*8+q holds
// h[n = kw*64 + half*32 + g*8 + q][o = cf*16 + r].
__global__ void k_proj_mfma(const __hip_bfloat16* __restrict__ xbf,
                            const __hip_bfloat16* __restrict__ WaT,
                            const float* __restrict__ aatt,
                            __hip_bfloat16* __restrict__ hF,
                            float* __restrict__ f1, float* __restrict__ f2) {
    int tile = blockIdx.x, hd = blockIdx.y;
    int t = threadIdx.x, lane = t & 63, w = t >> 6;
    int r0 = tile * 64;
    int b = r0 >> 10;
    int n0 = r0 & 1023;
    int bh = b * HH + hd;
    int al = lane & 15, ah = lane >> 4;
    const __hip_bfloat16* xrow = xbf + (size_t)(r0 + w * 16 + al) * FF;
    const __hip_bfloat16* Wb = WaT + (size_t)hd * OO * FF;
    f32x4 z4 = {0.f, 0.f, 0.f, 0.f};
    f32x4 acc[4] = {z4, z4, z4, z4};
    for (int k0 = 0; k0 < FF; k0 += 32) {
        int k = k0 + ah * 8;
        short8 af = *(const short8*)&xrow[k];
#pragma unroll
        for (int cf = 0; cf < 4; ++cf) {
            int col = cf * 16 + al;
            short8 bf = *(const short8*)&Wb[(size_t)col * FF + k];
            acc[cf] = __builtin_amdgcn_mfma_f32_16x16x32_bf16(af, bf, acc[cf], 0, 0, 0);
        }
    }
    int kw = tile & 15;
    int half = w >> 1;
    int hg = (w & 1) * 2 + (ah >> 1);
    int q0 = (ah & 1) * 4;
#pragma unroll
    for (int cf = 0; cf < 4; ++cf) {
        size_t base = ((((size_t)bh * 16 + kw) * 4 + cf) * 2 + half) * 512 +
                      (hg * 16 + al) * 8 + q0;
        s16x4 v;
#pragma unroll
        for (int r = 0; r < 4; ++r) v[r] = bf16s(acc[cf][r]);
        *(s16x4*)&hF[base] = v;
    }
    int nb = n0 + w * 16 + ah * 4;
    float p1[4] = {0.f, 0.f, 0.f, 0.f}, p2[4] = {0.f, 0.f, 0.f, 0.f};
#pragma unroll
    for (int cf = 0; cf < 4; ++cf) {
        int col = cf * 16 + al;
        float a1 = aatt[hd * 2 * OO + col];
        float a2 = aatt[hd * 2 * OO + OO + col];
#pragma unroll
        for (int r = 0; r < 4; ++r) {
            p1[r] += acc[cf][r] * a1;
            p2[r] += acc[cf][r] * a2;
        }
    }
#pragma unroll
    for (int off = 1; off < 16; off <<= 1) {
#pragma unroll
        for (int r = 0; r < 4; ++r) {
            p1[r] += __shfl_xor(p1[r], off);
            p2[r] += __shfl_xor(p2[r], off);
        }
    }
    if (al == 0) {
#pragma unroll
        for (int r = 0; r < 4; ++r) {
            f1[(size_t)bh * NN + nb + r] = p1[r];
            f2[(size_t)bh * NN + nb + r] = p2[r];
        }
    }
}

// ---------- FUSED att v6: 256 thr non-redundant A + double-buffered B prefetch --
__global__ void k_att_fused(const u64* __restrict__ adjbit, const float* __restrict__ f1,
                            const float* __restrict__ f2,
                            const __hip_bfloat16* __restrict__ hF,
                            __hip_bfloat16* __restrict__ ybf) {
    int orig = blockIdx.x;                     // 1024 blocks
    int wgid = (orig & 7) * 128 + (orig >> 3); // XCD-contiguous
    int bh = wgid >> 4;
    int n0 = (wgid & 15) * 64;
    int b = bh >> 3, hd = bh & 7;
    int t = threadIdx.x, lane = t & 63, w = t >> 6;
    __shared__ float Qs[1024], Ss[1024];
    __shared__ u64 bits[64 * 17];
    const float* f2b = f2 + (size_t)bh * NN;
    for (int j = t; j < 1024; j += 256) {
        float v = f2b[j];
        Qs[j] = __expf(v);
        Ss[j] = __expf(0.2f * v);
    }
    for (int e = t; e < 1024; e += 256) {
        int rr = e >> 4, c = e & 15;
        bits[rr * 17 + c] = adjbit[((size_t)b * NN + n0 + rr) * 16 + c];
    }
    int g = lane >> 4, r = lane & 15;
    int row = w * 16 + r;
    float fl = f1[(size_t)bh * NN + n0 + row];
    float P = __expf(fl), R = __expf(0.2f * fl);
    __syncthreads();
    const __hip_bfloat16* hFb = hF + (size_t)bh * 16 * 4 * 2 * 512 + lane * 8;
    f32x4 z4 = {0.f, 0.f, 0.f, 0.f};
    f32x4 acc[4] = {z4, z4, z4, z4};
    float ps = 0.f;
    int c0 = g * 8;
    auto BUILD = [&](int kw, short8& a0, short8& a1) {
        int k0 = kw * 64;
        u64 m = bits[row * 17 + kw];
        unsigned bl0 = (unsigned)(m >> c0) & 0xffu;
        unsigned bl1 = (unsigned)((m >> 32) >> c0) & 0xffu;
        f32x4 qa0 = *(const f32x4*)&Qs[k0 + c0];
        f32x4 qb0 = *(const f32x4*)&Qs[k0 + c0 + 4];
        f32x4 sa0 = *(const f32x4*)&Ss[k0 + c0];
        f32x4 sb0 = *(const f32x4*)&Ss[k0 + c0 + 4];
        f32x4 qa1 = *(const f32x4*)&Qs[k0 + 32 + c0];
        f32x4 qb1 = *(const f32x4*)&Qs[k0 + 32 + c0 + 4];
        f32x4 sa1 = *(const f32x4*)&Ss[k0 + 32 + c0];
        f32x4 sb1 = *(const f32x4*)&Ss[k0 + 32 + c0 + 4];
#pragma unroll
        for (int e = 0; e < 4; ++e) {
            float v0 = ((bl0 >> e) & 1) ? fmaxf(P * qa0[e], R * sa0[e]) : 0.f;
            float v1 = ((bl0 >> (4 + e)) & 1) ? fmaxf(P * qb0[e], R * sb0[e]) : 0.f;
            float v2 = ((bl1 >> e) & 1) ? fmaxf(P * qa1[e], R * sa1[e]) : 0.f;
            float v3 = ((bl1 >> (4 + e)) & 1) ? fmaxf(P * qb1[e], R * sb1[e]) : 0.f;
            ps += (v0 + v1) + (v2 + v3);
            a0[e] = bf16s(v0);
            a0[4 + e] = bf16s(v1);
            a1[e] = bf16s(v2);
            a1[4 + e] = bf16s(v3);
        }
    };
    auto LOADB = [&](int kw, short8* d0, short8* d1) {
#pragma unroll
        for (int cf = 0; cf < 4; ++cf) {
            const __hip_bfloat16* blk = hFb + ((size_t)(kw * 4 + cf) * 2) * 512;
            d0[cf] = *(const short8*)&blk[0];
            d1[cf] = *(const short8*)&blk[512];
        }
    };
    short8 pA0[4], pA1[4], pB0[4], pB1[4];
    LOADB(0, pA0, pA1);
    for (int kp = 0; kp < 8; ++kp) {
        short8 a0, a1;
        BUILD(2 * kp, a0, a1);
        LOADB(2 * kp + 1, pB0, pB1);
#pragma unroll
        for (int cf = 0; cf < 4; ++cf) {
            acc[cf] = __builtin_amdgcn_mfma_f32_16x16x32_bf16(a0, pA0[cf], acc[cf], 0, 0, 0);
            acc[cf] = __builtin_amdgcn_mfma_f32_16x16x32_bf16(a1, pA1[cf], acc[cf], 0, 0, 0);
        }
        BUILD(2 * kp + 1, a0, a1);
        if (kp < 7) LOADB(2 * kp + 2, pA0, pA1);
#pragma unroll
        for (int cf = 0; cf < 4; ++cf) {
            acc[cf] = __builtin_amdgcn_mfma_f32_16x16x32_bf16(a0, pB0[cf], acc[cf], 0, 0, 0);
            acc[cf] = __builtin_amdgcn_mfma_f32_16x16x32_bf16(a1, pB1[cf], acc[cf], 0, 0, 0);
        }
    }
    ps += __shfl_xor(ps, 16);
    ps += __shfl_xor(ps, 32);
#pragma unroll
    for (int rr = 0; rr < 4; ++rr) {
        int rloc = g * 4 + rr;
        float dn = __shfl(ps, rloc);
        float ids = 1.0f / dn;
        int nrow = n0 + w * 16 + rloc;
#pragma unroll
        for (int cf = 0; cf < 4; ++cf) {
            float v = acc[cf][rr] * ids;
            float e = v > 0.f ? v : expm1f(v);
            float yv = e > 0.f ? e : 0.01f * e;
            ybf[((size_t)b * NN + nrow) * 512 + hd * OO + cf * 16 + r] =
                __float2bfloat16(yv);
        }
    }
}

// ---------- MFMA outproj v2: 512 thr, 16-row tiles, 8 waves x 32 cols ----------
// hoF block (b, kw, cfB, half) of 512 bf16: elem (g*16+r)*8+q holds
// ho[n = kw*64 + half*32 + g*8 + q][c = cfB*16 + r].
__global__ void k_outproj_mfma(const __hip_bfloat16* __restrict__ ybf,
                               const __hip_bfloat16* __restrict__ WoT,
                               const float* __restrict__ ao,
                               __hip_bfloat16* __restrict__ hoF,
                               float* __restrict__ g1, float* __restrict__ g2) {
    int orig = blockIdx.x;                    // 512 blocks
    int tile = (orig & 7) * 64 + (orig >> 3); // XCD swizzle
    int t = threadIdx.x, lane = t & 63, w = t >> 6;   // 8 waves
    int r0 = tile * 16;
    int b = r0 >> 10;
    __shared__ __align__(16) __hip_bfloat16 As[16][520];
    __shared__ float pg1[8][16], pg2[8][16];
    for (int e = t; e < 1024; e += 512) {
        int row = e >> 6, k8 = (e & 63) * 8;
        *(short8*)&As[row][k8] = *(const short8*)&ybf[(size_t)(r0 + row) * 512 + k8];
    }
    __syncthreads();
    int al = lane & 15, ah = lane >> 4;
    f32x4 z4 = {0.f, 0.f, 0.f, 0.f};
    f32x4 acc[2] = {z4, z4};
    for (int k0 = 0; k0 < 512; k0 += 32) {
        int k = k0 + ah * 8;
        short8 a0 = *(const short8*)&As[al][k];
#pragma unroll
        for (int cf = 0; cf < 2; ++cf) {
            int col = w * 32 + cf * 16 + al;
            short8 bf = *(const short8*)&WoT[(size_t)col * 512 + k];
            acc[cf] = __builtin_amdgcn_mfma_f32_16x16x32_bf16(a0, bf, acc[cf], 0, 0, 0);
        }
    }
    int kw = (tile & 63) >> 2;
    int half = (tile >> 1) & 1;
    int hg0 = (tile & 1) * 2 + (ah >> 1);
    int q0 = (ah & 1) * 4;
    float q1[4] = {0.f, 0.f, 0.f, 0.f};
    float q2[4] = {0.f, 0.f, 0.f, 0.f};
#pragma unroll
    for (int cf = 0; cf < 2; ++cf) {
        int col = w * 32 + cf * 16 + al;
        int cfB = w * 2 + cf;
        float a1v = ao[col], a2v = ao[CC + col];
        size_t base = ((((size_t)b * 16 + kw) * 16 + cfB) * 2 + half) * 512;
        s16x4 v0;
#pragma unroll
        for (int r = 0; r < 4; ++r) {
            v0[r] = bf16s(acc[cf][r]);
            q1[r] += acc[cf][r] * a1v;
            q2[r] += acc[cf][r] * a2v;
        }
        *(s16x4*)&hoF[base + (hg0 * 16 + al) * 8 + q0] = v0;
    }
#pragma unroll
    for (int off = 1; off < 16; off <<= 1) {
#pragma unroll
        for (int j = 0; j < 4; ++j) {
            q1[j] += __shfl_xor(q1[j], off);
            q2[j] += __shfl_xor(q2[j], off);
        }
    }
    if (al == 0) {
#pragma unroll
        for (int j = 0; j < 4; ++j) {
            pg1[w][ah * 4 + j] = q1[j];
            pg2[w][ah * 4 + j] = q2[j];
        }
    }
    __syncthreads();
    if (t < 16) {
        float s1 = 0.f, s2 = 0.f;
#pragma unroll
        for (int ww = 0; ww < 8; ++ww) {
            s1 += pg1[ww][t];
            s2 += pg2[ww][t];
        }
        g1[r0 + t] = s1;
        g2[r0 + t] = s2;
    }
}

// ---------- FUSED out v8b: 512 thr, register A + B-prefetch + xin prefetch ------
__global__ void k_out_fused(const u64* __restrict__ adjbit, const float* __restrict__ g1,
                            const float* __restrict__ g2,
                            const __hip_bfloat16* __restrict__ hoF,
                            const float* __restrict__ xin, const int* __restrict__ mask,
                            const float* __restrict__ lw, const float* __restrict__ lb,
                            float* __restrict__ xout, __hip_bfloat16* __restrict__ xbfout,
                            float* __restrict__ outf, int final_) {
    int orig = blockIdx.x;                    // 512 blocks
    int wgid = (orig & 7) * 64 + (orig >> 3);
    int b = wgid >> 6;
    int n0 = (wgid & 63) * 16;
    int t = threadIdx.x, lane = t & 63, w = t >> 6;   // 8 waves
    __shared__ float Qs[1024], Ss[1024];
    __shared__ u64 bits[16 * 17];
    __shared__ float lns[8][16], lnq[8][16];
    const float* g2b = g2 + (size_t)b * NN;
    for (int j = t; j < 1024; j += 512) {
        float v = g2b[j];
        Qs[j] = __expf(v);
        Ss[j] = __expf(0.2f * v);
    }
    if (t < 256) {
        int rr = t >> 4, c = t & 15;
        bits[rr * 17 + c] = adjbit[((size_t)b * NN + n0 + rr) * 16 + c];
    }
    int g = lane >> 4, r = lane & 15;
    float gl = g1[(size_t)b * NN + n0 + r];
    float P = __expf(gl);
    float R = __expf(0.2f * gl);
    // ---- prefetch residual inputs + mask for this thread's epilogue elements ----
    float xv[4][2];
    int mkv[4];
#pragma unroll
    for (int rr = 0; rr < 4; ++rr) {
        int rloc = g * 4 + rr;
        int nrow = n0 + rloc;
        mkv[rr] = mask[b * NN + nrow];
        size_t rowo = ((size_t)b * NN + nrow) * CC;
#pragma unroll
        for (int cf = 0; cf < 2; ++cf) {
            int col = w * 32 + cf * 16 + r;
            xv[rr][cf] = xin[rowo + col];
        }
    }
    __syncthreads();
    const __hip_bfloat16* hoFb = hoF + (size_t)b * 16 * 16 * 2 * 512 + lane * 8;
    f32x4 z4 = {0.f, 0.f, 0.f, 0.f};
    f32x4 acc[2] = {z4, z4};
    float ps = 0.f;
    int c0 = g * 8;
    auto BUILD = [&](int kw, short8& a0, short8& a1) {
        int k0 = kw * 64;
        u64 m = bits[r * 17 + kw];
        unsigned bl0 = (unsigned)(m >> c0) & 0xffu;
        unsigned bl1 = (unsigned)((m >> 32) >> c0) & 0xffu;
        f32x4 qa0 = *(const f32x4*)&Qs[k0 + c0];
        f32x4 qb0 = *(const f32x4*)&Qs[k0 + c0 + 4];
        f32x4 sa0 = *(const f32x4*)&Ss[k0 + c0];
        f32x4 sb0 = *(const f32x4*)&Ss[k0 + c0 + 4];
        f32x4 qa1 = *(const f32x4*)&Qs[k0 + 32 + c0];
        f32x4 qb1 = *(const f32x4*)&Qs[k0 + 32 + c0 + 4];
        f32x4 sa1 = *(const f32x4*)&Ss[k0 + 32 + c0];
        f32x4 sb1 = *(const f32x4*)&Ss[k0 + 32 + c0 + 4];
#pragma unroll
        for (int e = 0; e < 4; ++e) {
            float v0 = ((bl0 >> e) & 1) ? fmaxf(P * qa0[e], R * sa0[e]) : 0.f;
            float v1 = ((bl0 >> (4 + e)) & 1) ? fmaxf(P * qb0[e], R * sb0[e]) : 0.f;
            float v2 = ((bl1 >> e) & 1) ? fmaxf(P * qa1[e], R * sa1[e]) : 0.f;
            float v3 = ((bl1 >> (4 + e)) & 1) ? fmaxf(P * qb1[e], R * sb1[e]) : 0.f;
            ps += (v0 + v1) + (v2 + v3);
            a0[e] = bf16s(v0);
            a0[4 + e] = bf16s(v1);
            a1[e] = bf16s(v2);
            a1[4 + e] = bf16s(v3);
        }
    };
    auto LOADB = [&](int kw, short8* d0, short8* d1) {
#pragma unroll
        for (int cf = 0; cf < 2; ++cf) {
            int cfB = w * 2 + cf;
            const __hip_bfloat16* blk = hoFb + ((size_t)(kw * 16 + cfB) * 2) * 512;
            d0[cf] = *(const short8*)&blk[0];
            d1[cf] = *(const short8*)&blk[512];
        }
    };
    short8 pA0[2], pA1[2], pB0[2], pB1[2];
    LOADB(0, pA0, pA1);
    for (int kp = 0; kp < 8; ++kp) {
        short8 a0, a1;
        BUILD(2 * kp, a0, a1);
        LOADB(2 * kp + 1, pB0, pB1);
#pragma unroll
        for (int cf = 0; cf < 2; ++cf) {
            acc[cf] = __builtin_amdgcn_mfma_f32_16x16x32_bf16(a0, pA0[cf], acc[cf], 0, 0, 0);
            acc[cf] = __builtin_amdgcn_mfma_f32_16x16x32_bf16(a1, pA1[cf], acc[cf], 0, 0, 0);
        }
        BUILD(2 * kp + 1, a0, a1);
        if (kp < 7) LOADB(2 * kp + 2, pA0, pA1);
#pragma unroll
        for (int cf = 0; cf < 2; ++cf) {
            acc[cf] = __builtin_amdgcn_mfma_f32_16x16x32_bf16(a0, pB0[cf], acc[cf], 0, 0, 0);
            acc[cf] = __builtin_amdgcn_mfma_f32_16x16x32_bf16(a1, pB1[cf], acc[cf], 0, 0, 0);
        }
    }
    ps += __shfl_xor(ps, 16);
    ps += __shfl_xor(ps, 32);
    float tv[4][2];
#pragma unroll
    for (int rr = 0; rr < 4; ++rr) {
        int rloc = g * 4 + rr;
        float dn = __shfl(ps, rloc);
        float ids = 1.0f / dn;
        float s1 = 0.f, s2 = 0.f;
#pragma unroll
        for (int cf = 0; cf < 2; ++cf) {
            float v = acc[cf][rr] * ids;
            float e = v > 0.f ? v : expm1f(v);
            float tvv = (mkv[rr] == 0) ? 0.f : (xv[rr][cf] + e);
            tv[rr][cf] = tvv;
            s1 += tvv;
            s2 += tvv * tvv;
        }
#pragma unroll
        for (int off = 1; off < 16; off <<= 1) {
            s1 += __shfl_xor(s1, off);
            s2 += __shfl_xor(s2, off);
        }
        if (r == 0) {
            lns[w][rloc] = s1;
            lnq[w][rloc] = s2;
        }
    }
    __syncthreads();
#pragma unroll
    for (int rr = 0; rr < 4; ++rr) {
        int rloc = g * 4 + rr;
        int nrow = n0 + rloc;
        size_t rowo = ((size_t)b * NN + nrow) * CC;
        float su = 0.f, sq = 0.f;
#pragma unroll
        for (int ww = 0; ww < 8; ++ww) {
            su += lns[ww][rloc];
            sq += lnq[ww][rloc];
        }
        float mu = su * (1.0f / CC);
        float var = sq * (1.0f / CC) - mu * mu;
        float rstd = rsqrtf(var + 1e-5f);
#pragma unroll
        for (int cf = 0; cf < 2; ++cf) {
            int col = w * 32 + cf * 16 + r;
            float ln = (tv[rr][cf] - mu) * rstd * lw[col] + lb[col];
            if (final_) {
                float rv = ln > 0.f ? ln : 0.f;
                outf[rowo + col] = rv;
                if (nrow == 0) outf[(size_t)BB * NN * CC + b * CC + col] = rv;
            } else {
                xout[rowo + col] = ln;
                xbfout[rowo + col] = __float2bfloat16(ln);
            }
        }
    }
}

extern "C" void kernel_launch(void* const* d_in, const int* in_sizes, int n_in,
                              void* d_out, int out_size, void* d_ws, size_t ws_size,
                              hipStream_t stream) {
    const float* x = (const float*)d_in[0];
    const int* adj = (const int*)d_in[1];
    const int* mask = (const int*)d_in[2];
    const float* W_att = (const float*)d_in[3];
    const float* a_att = (const float*)d_in[4];
    const float* W_out = (const float*)d_in[5];
    const float* a_out = (const float*)d_in[6];
    const float* ln_w = (const float*)d_in[7];
    const float* ln_b = (const float*)d_in[8];
    float* out = (float*)d_out;

    float* ws = (float*)d_ws;
    float* xbuf = ws;                          // 2,097,152 f32
    float* xbfr = xbuf + 2097152;              // 2,097,152 f32 slot (xbf)
    float* f1   = xbfr + 2097152;              // 65,536
    float* f2   = f1 + 65536;                  // 65,536
    float* g1   = f2 + 65536;                  // 8,192
    float* g2   = g1 + 8192;                   // 8,192
    float* p    = g2 + 8192;
    __hip_bfloat16* xbf = (__hip_bfloat16*)xbfr;          // 2,097,152 bf16
    __hip_bfloat16* hF  = (__hip_bfloat16*)p;             // 4,194,304 bf16 (8 MB)
    __hip_bfloat16* ybf = (__hip_bfloat16*)(p + 2097152); // 4,194,304 bf16
    __hip_bfloat16* hoF = (__hip_bfloat16*)(p + 4194304); // 2,097,152 bf16 (4 MB)
    __hip_bfloat16* WaT = (__hip_bfloat16*)(p + 5242880); // 131,072 bf16
    __hip_bfloat16* WoT = (__hip_bfloat16*)(p + 5308416); // 131,072 bf16
    u64* adjbit = (u64*)(p + 5373952);                    // 131,072 u64 (1 MB)

    k_prep<<<32768 + 8192 + 1024, 256, 0, stream>>>(adj, x, W_att, W_out,
                                                    adjbit, xbf, WaT, WoT);

    for (int layer = 0; layer < 2; ++layer) {
        const float* xin_l = layer ? xbuf : x;
        k_proj_mfma<<<dim3(128, 8), 256, 0, stream>>>(xbf, WaT, a_att, hF, f1, f2);
        k_att_fused<<<1024, 256, 0, stream>>>(adjbit, f1, f2, hF, ybf);
        k_outproj_mfma<<<512, 512, 0, stream>>>(ybf, WoT, a_out, hoF, g1, g2);
        k_out_fused<<<512, 512, 0, stream>>>(adjbit, g1, g2, hoF, xin_l, mask,
                                             ln_w, ln_b, xbuf, xbf, out, layer == 1);
    }
}